// Round 2
// baseline (3201.395 us; speedup 1.0000x reference)
//
#include <hip/hip_runtime.h>
#include <hip/hip_bf16.h>

#define DIM 1024
#define HID 2816
#define NEXP 7
#define TOKENS 8192

typedef __bf16 bf16x8 __attribute__((ext_vector_type(8)));
typedef float f32x4 __attribute__((ext_vector_type(4)));

static __device__ __forceinline__ unsigned short f2b(float f) {
  union { float f; unsigned int i; } c; c.f = f;
  unsigned int i = c.i;
  unsigned int r = (i + 0x7fffu + ((i >> 16) & 1u)) >> 16;
  return (unsigned short)r;
}

// ---------------- router: probs = sigmoid((x@Wr)*bias); top2 -> normalized weights ----------------
__global__ __launch_bounds__(256, 2) void router_kernel(
    const float* __restrict__ X,
    const float* __restrict__ Wr,
    const float* __restrict__ bias,
    float* __restrict__ wout)
{
  __shared__ float wr[DIM * NEXP];
  for (int i = threadIdx.x; i < DIM * NEXP; i += 256) wr[i] = Wr[i];
  __syncthreads();
  int t = blockIdx.x * 256 + threadIdx.x;
  float acc[NEXP];
#pragma unroll
  for (int e = 0; e < NEXP; ++e) acc[e] = 0.f;
  const float* xp = X + (size_t)t * DIM;
  for (int d0 = 0; d0 < DIM; d0 += 4) {
    float4 xv = *(const float4*)(xp + d0);
    const float* xs = (const float*)&xv;
#pragma unroll
    for (int j = 0; j < 4; ++j) {
      float xf = xs[j];
#pragma unroll
      for (int e = 0; e < NEXP; ++e) acc[e] += xf * wr[(d0 + j) * NEXP + e];
    }
  }
  float p[NEXP];
#pragma unroll
  for (int e = 0; e < NEXP; ++e)
    p[e] = 1.f / (1.f + __expf(-acc[e] * bias[e]));
  float best = -1.f; int bi = 0;
#pragma unroll
  for (int e = 0; e < NEXP; ++e) if (p[e] > best) { best = p[e]; bi = e; }
  float sec = -1.f; int si = 0;
#pragma unroll
  for (int e = 0; e < NEXP; ++e) if (e != bi && p[e] > sec) { sec = p[e]; si = e; }
  float s = best + sec;
  float w0 = best / s, w1 = sec / s;
#pragma unroll
  for (int e = 0; e < NEXP; ++e)
    wout[t * NEXP + e] = (e == bi) ? w0 : ((e == si) ? w1 : 0.f);
}

// ---------------- fused gate+up GEMM: H = silu(X@Wg) * (X@Wu)  (fp32 in, bf16 out) ----------------
// block tile 128(tokens) x 64(hid), 4 waves each 64x32, BK=32
__global__ __launch_bounds__(256, 2) void gateup_kernel(
    const float* __restrict__ X,
    const float* __restrict__ Wg,
    const float* __restrict__ Wu,
    unsigned short* __restrict__ H)
{
  __shared__ __align__(16) unsigned short As[128 * 32];
  __shared__ __align__(16) unsigned short Bgs[64 * 48];
  __shared__ __align__(16) unsigned short Bus[64 * 48];
  const int m0 = blockIdx.y * 128;
  const int n0 = blockIdx.x * 64;
  const int tid = threadIdx.x;
  const int lane = tid & 63;
  const int wid = tid >> 6;
  const int wm = (wid & 1) * 64;
  const int wn = (wid >> 1) * 32;
  const int c = lane & 15;
  const int q = lane >> 4;

  f32x4 accg[4][2], accu[4][2];
#pragma unroll
  for (int mi = 0; mi < 4; ++mi)
#pragma unroll
    for (int ni = 0; ni < 2; ++ni) {
      accg[mi][ni] = {0.f, 0.f, 0.f, 0.f};
      accu[mi][ni] = {0.f, 0.f, 0.f, 0.f};
    }

  const int ar = tid >> 2;          // 0..63
  const int ak = (tid & 3) * 8;     // 0,8,16,24
  const int bk = tid & 31;          // 0..31
  const int bn8 = (tid >> 5) * 8;   // 0..56

  for (int k0 = 0; k0 < DIM; k0 += 32) {
    __syncthreads();
    // A: fp32 -> bf16 into LDS, rows ar and ar+64
#pragma unroll
    for (int h = 0; h < 2; ++h) {
      const float* px = &X[(size_t)(m0 + ar + h * 64) * DIM + k0 + ak];
      float4 u0 = *(const float4*)px;
      float4 u1 = *(const float4*)(px + 4);
      unsigned short tmp[8];
      tmp[0] = f2b(u0.x); tmp[1] = f2b(u0.y); tmp[2] = f2b(u0.z); tmp[3] = f2b(u0.w);
      tmp[4] = f2b(u1.x); tmp[5] = f2b(u1.y); tmp[6] = f2b(u1.z); tmp[7] = f2b(u1.w);
      *(int4*)&As[(ar + h * 64) * 32 + ak] = *(const int4*)tmp;
    }
    // B: fp32 -> bf16 transposed into LDS ([n][k], stride 48)
    {
      const float* pg = &Wg[(size_t)(k0 + bk) * HID + n0 + bn8];
      const float* pu = &Wu[(size_t)(k0 + bk) * HID + n0 + bn8];
      float4 g0 = *(const float4*)pg, g1 = *(const float4*)(pg + 4);
      float4 u0 = *(const float4*)pu, u1 = *(const float4*)(pu + 4);
      float gf[8] = {g0.x, g0.y, g0.z, g0.w, g1.x, g1.y, g1.z, g1.w};
      float uf[8] = {u0.x, u0.y, u0.z, u0.w, u1.x, u1.y, u1.z, u1.w};
#pragma unroll
      for (int i = 0; i < 8; ++i) {
        Bgs[(bn8 + i) * 48 + bk] = f2b(gf[i]);
        Bus[(bn8 + i) * 48 + bk] = f2b(uf[i]);
      }
    }
    __syncthreads();
    bf16x8 a[4], bg[2], bu[2];
#pragma unroll
    for (int mi = 0; mi < 4; ++mi)
      a[mi] = *(const bf16x8*)&As[(wm + mi * 16 + c) * 32 + q * 8];
#pragma unroll
    for (int ni = 0; ni < 2; ++ni) {
      bg[ni] = *(const bf16x8*)&Bgs[(wn + ni * 16 + c) * 48 + q * 8];
      bu[ni] = *(const bf16x8*)&Bus[(wn + ni * 16 + c) * 48 + q * 8];
    }
#pragma unroll
    for (int mi = 0; mi < 4; ++mi)
#pragma unroll
      for (int ni = 0; ni < 2; ++ni) {
        accg[mi][ni] = __builtin_amdgcn_mfma_f32_16x16x32_bf16(a[mi], bg[ni], accg[mi][ni], 0, 0, 0);
        accu[mi][ni] = __builtin_amdgcn_mfma_f32_16x16x32_bf16(a[mi], bu[ni], accu[mi][ni], 0, 0, 0);
      }
  }
#pragma unroll
  for (int mi = 0; mi < 4; ++mi)
#pragma unroll
    for (int ni = 0; ni < 2; ++ni)
#pragma unroll
      for (int r = 0; r < 4; ++r) {
        int row = wm + mi * 16 + q * 4 + r;
        int col = wn + ni * 16 + c;
        float g = accg[mi][ni][r];
        float u = accu[mi][ni][r];
        float h = (g / (1.f + __expf(-g))) * u;
        H[(size_t)(m0 + row) * HID + n0 + col] = f2b(h);
      }
}

// ---------------- down GEMM: out (+)= (H @ Wd) * w[t]  (bf16 H, fp32 Wd, fp32 out) ----------------
// block tile 128x128, 4 waves each 64x64, BK=32
template <bool ACCUM>
__global__ __launch_bounds__(256, 2) void down_kernel(
    const unsigned short* __restrict__ Hm,
    const float* __restrict__ Wd,
    const float* __restrict__ w,   // pre-offset by expert; stride NEXP. null if !ACCUM
    float* __restrict__ out)
{
  __shared__ __align__(16) unsigned short As[128 * 32];
  __shared__ __align__(16) unsigned short Bs[128 * 48];
  const int m0 = blockIdx.y * 128;
  const int n0 = blockIdx.x * 128;
  const int tid = threadIdx.x;
  const int lane = tid & 63;
  const int wid = tid >> 6;
  const int wm = (wid & 1) * 64;
  const int wn = (wid >> 1) * 64;
  const int c = lane & 15;
  const int q = lane >> 4;

  f32x4 acc[4][4];
#pragma unroll
  for (int mi = 0; mi < 4; ++mi)
#pragma unroll
    for (int ni = 0; ni < 4; ++ni) acc[mi][ni] = {0.f, 0.f, 0.f, 0.f};

  const int ar = tid >> 2;
  const int ak = (tid & 3) * 8;
  const int bk = tid & 31;
  const int bn8 = (tid >> 5) * 8;

  for (int k0 = 0; k0 < HID; k0 += 32) {
    __syncthreads();
    // A: bf16 H, direct int4 copy
    *(int4*)&As[ar * 32 + ak] = *(const int4*)&Hm[(size_t)(m0 + ar) * HID + k0 + ak];
    *(int4*)&As[(ar + 64) * 32 + ak] = *(const int4*)&Hm[(size_t)(m0 + ar + 64) * HID + k0 + ak];
    // B: fp32 -> bf16 transposed, two 8-wide n segments (cols n0..n0+127)
    {
      const float* p0 = &Wd[(size_t)(k0 + bk) * DIM + n0 + bn8];
      const float* p1 = p0 + 64;
      float4 a0 = *(const float4*)p0, a1 = *(const float4*)(p0 + 4);
      float4 b0 = *(const float4*)p1, b1 = *(const float4*)(p1 + 4);
      float f0[8] = {a0.x, a0.y, a0.z, a0.w, a1.x, a1.y, a1.z, a1.w};
      float f1[8] = {b0.x, b0.y, b0.z, b0.w, b1.x, b1.y, b1.z, b1.w};
#pragma unroll
      for (int i = 0; i < 8; ++i) {
        Bs[(bn8 + i) * 48 + bk] = f2b(f0[i]);
        Bs[(bn8 + 64 + i) * 48 + bk] = f2b(f1[i]);
      }
    }
    __syncthreads();
    bf16x8 a[4], b[4];
#pragma unroll
    for (int mi = 0; mi < 4; ++mi)
      a[mi] = *(const bf16x8*)&As[(wm + mi * 16 + c) * 32 + q * 8];
#pragma unroll
    for (int ni = 0; ni < 4; ++ni)
      b[ni] = *(const bf16x8*)&Bs[(wn + ni * 16 + c) * 48 + q * 8];
#pragma unroll
    for (int mi = 0; mi < 4; ++mi)
#pragma unroll
      for (int ni = 0; ni < 4; ++ni)
        acc[mi][ni] = __builtin_amdgcn_mfma_f32_16x16x32_bf16(a[mi], b[ni], acc[mi][ni], 0, 0, 0);
  }
#pragma unroll
  for (int mi = 0; mi < 4; ++mi)
#pragma unroll
    for (int r = 0; r < 4; ++r) {
      int trow = m0 + wm + mi * 16 + q * 4 + r;
      float wt = ACCUM ? w[(size_t)trow * NEXP] : 1.f;
#pragma unroll
      for (int ni = 0; ni < 4; ++ni) {
        int col = n0 + wn + ni * 16 + c;
        float v = acc[mi][ni][r] * wt;
        float* po = &out[(size_t)trow * DIM + col];
        if (ACCUM) *po += v; else *po = v;
      }
    }
}

extern "C" void kernel_launch(void* const* d_in, const int* in_sizes, int n_in,
                              void* d_out, int out_size, void* d_ws, size_t ws_size,
                              hipStream_t stream) {
  (void)in_sizes; (void)n_in; (void)out_size; (void)ws_size;
  const float* x   = (const float*)d_in[0];
  const float* sg  = (const float*)d_in[1];
  const float* su  = (const float*)d_in[2];
  const float* sd  = (const float*)d_in[3];
  const float* rg  = (const float*)d_in[4];
  const float* ru  = (const float*)d_in[5];
  const float* rd  = (const float*)d_in[6];
  const float* wrr = (const float*)d_in[7];
  const float* rb  = (const float*)d_in[8];
  float* out = (float*)d_out;

  char* ws = (char*)d_ws;
  unsigned short* Hbuf = (unsigned short*)ws;              // 8192*2816*2 = 46,137,344 B
  float* wbuf = (float*)(ws + 46137344);                   // 8192*7*4    =    229,376 B

  dim3 blk(256);
  router_kernel<<<dim3(TOKENS / 256), blk, 0, stream>>>(x, wrr, rb, wbuf);

  dim3 ggu(HID / 64, TOKENS / 128);
  dim3 gdn(DIM / 128, TOKENS / 128);

  // shared expert initializes out
  gateup_kernel<<<ggu, blk, 0, stream>>>(x, sg, su, Hbuf);
  down_kernel<false><<<gdn, blk, 0, stream>>>(Hbuf, sd, nullptr, out);

  // routed experts accumulate (dense, masked by router weight)
  for (int e = 0; e < NEXP; ++e) {
    gateup_kernel<<<ggu, blk, 0, stream>>>(
        x, rg + (size_t)e * DIM * HID, ru + (size_t)e * DIM * HID, Hbuf);
    down_kernel<true><<<gdn, blk, 0, stream>>>(
        Hbuf, rd + (size_t)e * HID * DIM, wbuf + e, out);
  }
}

// Round 3
// 1812.666 us; speedup vs baseline: 1.7661x; 1.7661x over previous
//
#include <hip/hip_runtime.h>
#include <hip/hip_bf16.h>

#define DIM 1024
#define HID 2816
#define NEXP 7
#define TOKENS 8192

typedef __bf16 bf16x8 __attribute__((ext_vector_type(8)));
typedef float f32x4 __attribute__((ext_vector_type(4)));

static __device__ __forceinline__ unsigned short f2b(float f) {
  union { float f; unsigned int i; } c; c.f = f;
  unsigned int i = c.i;
  unsigned int r = (i + 0x7fffu + ((i >> 16) & 1u)) >> 16;
  return (unsigned short)r;
}

// async global->LDS, 16 bytes per lane. LDS dest must be wave-uniform base + lane*16.
static __device__ __forceinline__ void gload16(const void* g, void* l) {
  __builtin_amdgcn_global_load_lds(
      (const __attribute__((address_space(1))) unsigned int*)g,
      (__attribute__((address_space(3))) unsigned int*)l, 16, 0, 0);
}

// ---------------- router: probs = sigmoid((x@Wr)*bias); top2 -> normalized weights ----------------
__global__ __launch_bounds__(256, 2) void router_kernel(
    const float* __restrict__ X,
    const float* __restrict__ Wr,
    const float* __restrict__ bias,
    float* __restrict__ wout)
{
  __shared__ float wr[DIM * NEXP];
  for (int i = threadIdx.x; i < DIM * NEXP; i += 256) wr[i] = Wr[i];
  __syncthreads();
  int t = blockIdx.x * 256 + threadIdx.x;
  float acc[NEXP];
#pragma unroll
  for (int e = 0; e < NEXP; ++e) acc[e] = 0.f;
  const float* xp = X + (size_t)t * DIM;
  for (int d0 = 0; d0 < DIM; d0 += 4) {
    float4 xv = *(const float4*)(xp + d0);
    const float* xs = (const float*)&xv;
#pragma unroll
    for (int j = 0; j < 4; ++j) {
      float xf = xs[j];
#pragma unroll
      for (int e = 0; e < NEXP; ++e) acc[e] += xf * wr[(d0 + j) * NEXP + e];
    }
  }
  float p[NEXP];
#pragma unroll
  for (int e = 0; e < NEXP; ++e)
    p[e] = 1.f / (1.f + __expf(-acc[e] * bias[e]));
  float best = -1.f; int bi = 0;
#pragma unroll
  for (int e = 0; e < NEXP; ++e) if (p[e] > best) { best = p[e]; bi = e; }
  float sec = -1.f; int si = 0;
#pragma unroll
  for (int e = 0; e < NEXP; ++e) if (e != bi && p[e] > sec) { sec = p[e]; si = e; }
  float s = best + sec;
  float w0 = best / s, w1 = sec / s;
#pragma unroll
  for (int e = 0; e < NEXP; ++e)
    wout[t * NEXP + e] = (e == bi) ? w0 : ((e == si) ? w1 : 0.f);
}

// ---------------- X fp32 -> bf16 ----------------
__global__ __launch_bounds__(256) void xcvt_kernel(
    const float* __restrict__ X, unsigned short* __restrict__ Xb)
{
  int i = (blockIdx.x * 256 + threadIdx.x) * 8;
  float4 v0 = *(const float4*)&X[i];
  float4 v1 = *(const float4*)&X[i + 4];
  unsigned short o[8];
  o[0] = f2b(v0.x); o[1] = f2b(v0.y); o[2] = f2b(v0.z); o[3] = f2b(v0.w);
  o[4] = f2b(v1.x); o[5] = f2b(v1.y); o[6] = f2b(v1.z); o[7] = f2b(v1.w);
  *(int4*)&Xb[i] = *(const int4*)o;
}

// ---------------- transpose + convert: W [K][N] fp32 -> WT [N][K] bf16, 64x64 tiles ----------------
// blockIdx.z selects (src0,dst0) or (src1,dst1) so gate+up go in one launch.
__global__ __launch_bounds__(256) void transpose_cvt_kernel(
    const float* __restrict__ src0, const float* __restrict__ src1,
    unsigned short* __restrict__ dst0, unsigned short* __restrict__ dst1,
    int K, int N)
{
  const float* src = blockIdx.z ? src1 : src0;
  unsigned short* dst = blockIdx.z ? dst1 : dst0;
  __shared__ unsigned short t[64][72];   // pad 72: row stride 144 B (16B-aligned)
  const int n0 = blockIdx.x * 64, k0 = blockIdx.y * 64;
  const int tid = threadIdx.x;
  const int kl = tid >> 4, nl = (tid & 15) * 4;
#pragma unroll
  for (int i = 0; i < 4; ++i) {
    int k = kl + i * 16;
    float4 v = *(const float4*)&src[(size_t)(k0 + k) * N + n0 + nl];
    t[nl + 0][k] = f2b(v.x); t[nl + 1][k] = f2b(v.y);
    t[nl + 2][k] = f2b(v.z); t[nl + 3][k] = f2b(v.w);
  }
  __syncthreads();
  const int nl2 = tid >> 3, kc = (tid & 7) * 8;
#pragma unroll
  for (int i = 0; i < 2; ++i) {
    int n = nl2 + i * 32;
    *(int4*)&dst[(size_t)(n0 + n) * K + k0 + kc] = *(const int4*)&t[n][kc];
  }
}

// ---------------- fused gate+up GEMM: H = silu(Xb@WgT^T) * (Xb@WuT^T) ----------------
// all-bf16, B pre-transposed [n][k]. Block tile 128(m)x64(n), 4 waves each 64x32 (g and u).
__global__ __launch_bounds__(256, 2) void gateup_kernel(
    const unsigned short* __restrict__ Xb,   // [TOKENS][DIM]
    const unsigned short* __restrict__ Wgu,  // [2][HID][DIM]
    unsigned short* __restrict__ H)          // [TOKENS][HID]
{
  __shared__ __align__(16) unsigned short As[128 * 32];
  __shared__ __align__(16) unsigned short Bgs[64 * 32];
  __shared__ __align__(16) unsigned short Bus[64 * 32];
  const int m0 = blockIdx.y * 128;
  const int n0 = blockIdx.x * 64;
  const int tid = threadIdx.x;
  const int lane = tid & 63;
  const int w = tid >> 6;
  const int wm = (w & 1) * 64;
  const int wn = (w >> 1) * 32;
  const int c = lane & 15;
  const int q = lane >> 4;

  const unsigned short* Wg = Wgu;
  const unsigned short* Wu = Wgu + (size_t)HID * DIM;

  // staging: chunk tid covers row tid>>2, k-offset (tid&3)*8 -> lds elem offset tid*8
  const int srow = tid >> 2;
  const int skofs = (tid & 3) * 8;
  const unsigned short* aptr0 = Xb + (size_t)(m0 + srow) * DIM + skofs;
  const unsigned short* aptr1 = Xb + (size_t)(m0 + srow + 64) * DIM + skofs;
  const unsigned short* gptr = Wg + (size_t)(n0 + srow) * DIM + skofs;
  const unsigned short* uptr = Wu + (size_t)(n0 + srow) * DIM + skofs;

  f32x4 accg[4][2], accu[4][2];
#pragma unroll
  for (int mi = 0; mi < 4; ++mi)
#pragma unroll
    for (int ni = 0; ni < 2; ++ni) {
      accg[mi][ni] = {0.f, 0.f, 0.f, 0.f};
      accu[mi][ni] = {0.f, 0.f, 0.f, 0.f};
    }

  for (int k0 = 0; k0 < DIM; k0 += 32) {
    __syncthreads();
    gload16(aptr0 + k0, &As[tid * 8]);
    gload16(aptr1 + k0, &As[2048 + tid * 8]);
    gload16(gptr + k0, &Bgs[tid * 8]);
    gload16(uptr + k0, &Bus[tid * 8]);
    __syncthreads();
    bf16x8 a[4], bg[2], bu[2];
#pragma unroll
    for (int mi = 0; mi < 4; ++mi)
      a[mi] = *(const bf16x8*)&As[(wm + mi * 16 + c) * 32 + q * 8];
#pragma unroll
    for (int ni = 0; ni < 2; ++ni) {
      bg[ni] = *(const bf16x8*)&Bgs[(wn + ni * 16 + c) * 32 + q * 8];
      bu[ni] = *(const bf16x8*)&Bus[(wn + ni * 16 + c) * 32 + q * 8];
    }
#pragma unroll
    for (int mi = 0; mi < 4; ++mi)
#pragma unroll
      for (int ni = 0; ni < 2; ++ni) {
        accg[mi][ni] = __builtin_amdgcn_mfma_f32_16x16x32_bf16(a[mi], bg[ni], accg[mi][ni], 0, 0, 0);
        accu[mi][ni] = __builtin_amdgcn_mfma_f32_16x16x32_bf16(a[mi], bu[ni], accu[mi][ni], 0, 0, 0);
      }
  }
#pragma unroll
  for (int mi = 0; mi < 4; ++mi)
#pragma unroll
    for (int ni = 0; ni < 2; ++ni)
#pragma unroll
      for (int r = 0; r < 4; ++r) {
        int row = wm + mi * 16 + q * 4 + r;
        int col = wn + ni * 16 + c;
        float g = accg[mi][ni][r];
        float u = accu[mi][ni][r];
        float h = (g / (1.f + __expf(-g))) * u;
        H[(size_t)(m0 + row) * HID + n0 + col] = f2b(h);
      }
}

// ---------------- down GEMM: out (+)= (H @ WdT^T) * w[t] ----------------
// all-bf16 inputs, fp32 out. Block tile 128x128, 4 waves each 64x64, BK=32.
template <bool ACCUM>
__global__ __launch_bounds__(256, 2) void down_kernel(
    const unsigned short* __restrict__ Hm,   // [TOKENS][HID]
    const unsigned short* __restrict__ WdT,  // [DIM][HID]
    const float* __restrict__ w,             // pre-offset by expert; stride NEXP. null if !ACCUM
    float* __restrict__ out)
{
  __shared__ __align__(16) unsigned short As[128 * 32];
  __shared__ __align__(16) unsigned short Bs[128 * 32];
  const int m0 = blockIdx.y * 128;
  const int n0 = blockIdx.x * 128;
  const int tid = threadIdx.x;
  const int lane = tid & 63;
  const int w4 = tid >> 6;
  const int wm = (w4 & 1) * 64;
  const int wn = (w4 >> 1) * 64;
  const int c = lane & 15;
  const int q = lane >> 4;

  const int srow = tid >> 2;
  const int skofs = (tid & 3) * 8;
  const unsigned short* aptr0 = Hm + (size_t)(m0 + srow) * HID + skofs;
  const unsigned short* aptr1 = Hm + (size_t)(m0 + srow + 64) * HID + skofs;
  const unsigned short* bptr0 = WdT + (size_t)(n0 + srow) * HID + skofs;
  const unsigned short* bptr1 = WdT + (size_t)(n0 + srow + 64) * HID + skofs;

  f32x4 acc[4][4];
#pragma unroll
  for (int mi = 0; mi < 4; ++mi)
#pragma unroll
    for (int ni = 0; ni < 4; ++ni) acc[mi][ni] = {0.f, 0.f, 0.f, 0.f};

  for (int k0 = 0; k0 < HID; k0 += 32) {
    __syncthreads();
    gload16(aptr0 + k0, &As[tid * 8]);
    gload16(aptr1 + k0, &As[2048 + tid * 8]);
    gload16(bptr0 + k0, &Bs[tid * 8]);
    gload16(bptr1 + k0, &Bs[2048 + tid * 8]);
    __syncthreads();
    bf16x8 a[4], b[4];
#pragma unroll
    for (int mi = 0; mi < 4; ++mi)
      a[mi] = *(const bf16x8*)&As[(wm + mi * 16 + c) * 32 + q * 8];
#pragma unroll
    for (int ni = 0; ni < 4; ++ni)
      b[ni] = *(const bf16x8*)&Bs[(wn + ni * 16 + c) * 32 + q * 8];
#pragma unroll
    for (int mi = 0; mi < 4; ++mi)
#pragma unroll
      for (int ni = 0; ni < 4; ++ni)
        acc[mi][ni] = __builtin_amdgcn_mfma_f32_16x16x32_bf16(a[mi], b[ni], acc[mi][ni], 0, 0, 0);
  }
#pragma unroll
  for (int mi = 0; mi < 4; ++mi)
#pragma unroll
    for (int r = 0; r < 4; ++r) {
      int trow = m0 + wm + mi * 16 + q * 4 + r;
      float wt = ACCUM ? w[(size_t)trow * NEXP] : 1.f;
#pragma unroll
      for (int ni = 0; ni < 4; ++ni) {
        int col = n0 + wn + ni * 16 + c;
        float v = acc[mi][ni][r] * wt;
        float* po = &out[(size_t)trow * DIM + col];
        if (ACCUM) *po += v; else *po = v;
      }
    }
}

extern "C" void kernel_launch(void* const* d_in, const int* in_sizes, int n_in,
                              void* d_out, int out_size, void* d_ws, size_t ws_size,
                              hipStream_t stream) {
  (void)in_sizes; (void)n_in; (void)out_size; (void)ws_size;
  const float* x   = (const float*)d_in[0];
  const float* sg  = (const float*)d_in[1];
  const float* su  = (const float*)d_in[2];
  const float* sd  = (const float*)d_in[3];
  const float* rg  = (const float*)d_in[4];
  const float* ru  = (const float*)d_in[5];
  const float* rd  = (const float*)d_in[6];
  const float* wrr = (const float*)d_in[7];
  const float* rb  = (const float*)d_in[8];
  float* out = (float*)d_out;

  char* ws = (char*)d_ws;
  unsigned short* Xb  = (unsigned short*)ws;               // 16,777,216 B
  unsigned short* H   = (unsigned short*)(ws + 16777216);  // 46,137,344 B
  unsigned short* Wgu = (unsigned short*)(ws + 62914560);  // 11,534,336 B
  unsigned short* Wd  = (unsigned short*)(ws + 74448896);  //  5,767,168 B
  float* wbuf         = (float*)(ws + 80216064);           //    229,376 B

  dim3 blk(256);
  router_kernel<<<dim3(TOKENS / 256), blk, 0, stream>>>(x, wrr, rb, wbuf);
  xcvt_kernel<<<dim3(TOKENS * DIM / (8 * 256)), blk, 0, stream>>>(x, Xb);

  dim3 ggu(HID / 64, TOKENS / 128);
  dim3 gdn(DIM / 128, TOKENS / 128);
  dim3 tgu(HID / 64, DIM / 64, 2);   // W[g|u]: K=DIM, N=HID
  dim3 tdn(DIM / 64, HID / 64, 1);   // Wd: K=HID, N=DIM

  for (int e = 0; e < 8; ++e) {
    const float* eg = (e == 0) ? sg : rg + (size_t)(e - 1) * DIM * HID;
    const float* eu = (e == 0) ? su : ru + (size_t)(e - 1) * DIM * HID;
    const float* ed = (e == 0) ? sd : rd + (size_t)(e - 1) * HID * DIM;
    transpose_cvt_kernel<<<tgu, blk, 0, stream>>>(eg, eu, Wgu, Wgu + (size_t)HID * DIM, DIM, HID);
    transpose_cvt_kernel<<<tdn, blk, 0, stream>>>(ed, ed, Wd, Wd, HID, DIM);
    gateup_kernel<<<ggu, blk, 0, stream>>>(Xb, Wgu, H);
    if (e == 0)
      down_kernel<false><<<gdn, blk, 0, stream>>>(H, Wd, nullptr, out);
    else
      down_kernel<true><<<gdn, blk, 0, stream>>>(H, Wd, wbuf + (e - 1), out);
  }
}

// Round 4
// 1299.618 us; speedup vs baseline: 2.4633x; 1.3948x over previous
//
#include <hip/hip_runtime.h>
#include <hip/hip_bf16.h>

#define DIM 1024
#define HID 2816
#define NEXP 7
#define TOKENS 8192

typedef __bf16 bf16x8 __attribute__((ext_vector_type(8)));
typedef float f32x4 __attribute__((ext_vector_type(4)));

static __device__ __forceinline__ unsigned short f2b(float f) {
  union { float f; unsigned int i; } c; c.f = f;
  unsigned int i = c.i;
  unsigned int r = (i + 0x7fffu + ((i >> 16) & 1u)) >> 16;
  return (unsigned short)r;
}

// async global->LDS, 16 bytes per lane. Global addr is per-lane; LDS dest = wave base + lane*16.
static __device__ __forceinline__ void gload16(const void* g, void* l) {
  __builtin_amdgcn_global_load_lds(
      (const __attribute__((address_space(1))) unsigned int*)g,
      (__attribute__((address_space(3))) unsigned int*)l, 16, 0, 0);
}

// ---------------- router: top2 of sigmoid((x@Wr)*bias), normalized -> (e0,e1,w0,w1) ----------------
__global__ __launch_bounds__(256, 2) void router_kernel(
    const float* __restrict__ X,
    const float* __restrict__ Wr,
    const float* __restrict__ bias,
    int* __restrict__ eidx,     // packed e0 | e1<<8
    float* __restrict__ ew)     // float2 (w0,w1)
{
  __shared__ float wr[DIM * NEXP];
  for (int i = threadIdx.x; i < DIM * NEXP; i += 256) wr[i] = Wr[i];
  __syncthreads();
  int t = blockIdx.x * 256 + threadIdx.x;
  float acc[NEXP];
#pragma unroll
  for (int e = 0; e < NEXP; ++e) acc[e] = 0.f;
  const float* xp = X + (size_t)t * DIM;
  for (int d0 = 0; d0 < DIM; d0 += 4) {
    float4 xv = *(const float4*)(xp + d0);
    const float* xs = (const float*)&xv;
#pragma unroll
    for (int j = 0; j < 4; ++j) {
      float xf = xs[j];
#pragma unroll
      for (int e = 0; e < NEXP; ++e) acc[e] += xf * wr[(d0 + j) * NEXP + e];
    }
  }
  float p[NEXP];
#pragma unroll
  for (int e = 0; e < NEXP; ++e)
    p[e] = 1.f / (1.f + __expf(-acc[e] * bias[e]));
  float best = -1.f; int bi = 0;
#pragma unroll
  for (int e = 0; e < NEXP; ++e) if (p[e] > best) { best = p[e]; bi = e; }
  float sec = -1.f; int si = 0;
#pragma unroll
  for (int e = 0; e < NEXP; ++e) if (e != bi && p[e] > sec) { sec = p[e]; si = e; }
  float s = best + sec;
  eidx[t] = bi | (si << 8);
  ((float2*)ew)[t] = make_float2(best / s, sec / s);
}

// ---------------- build per-expert slot lists ----------------
__global__ __launch_bounds__(256) void build_kernel(
    const int* __restrict__ eidx, const float* __restrict__ ew,
    int* __restrict__ tok, float* __restrict__ wgt, int* __restrict__ cntofs)
{
  __shared__ int cnt[NEXP], fill[NEXP], ofs[NEXP];
  if (threadIdx.x < NEXP) { cnt[threadIdx.x] = 0; fill[threadIdx.x] = 0; }
  __syncthreads();
  for (int t = threadIdx.x; t < TOKENS; t += 256) {
    int p = eidx[t];
    atomicAdd(&cnt[p & 0xff], 1);
    atomicAdd(&cnt[(p >> 8) & 0xff], 1);
  }
  __syncthreads();
  if (threadIdx.x == 0) {
    int o = 0;
    for (int e = 0; e < NEXP; ++e) { ofs[e] = o; cntofs[e] = cnt[e]; cntofs[8 + e] = o; o += cnt[e]; }
  }
  __syncthreads();
  for (int t = threadIdx.x; t < TOKENS; t += 256) {
    int p = eidx[t];
    int e0 = p & 0xff, e1 = (p >> 8) & 0xff;
    float2 w = ((const float2*)ew)[t];
    int p0 = ofs[e0] + atomicAdd(&fill[e0], 1);
    tok[p0] = t; wgt[p0] = w.x;
    int p1 = ofs[e1] + atomicAdd(&fill[e1], 1);
    tok[p1] = t; wgt[p1] = w.y;
  }
}

// ---------------- X fp32 -> bf16 ----------------
__global__ __launch_bounds__(256) void xcvt_kernel(
    const float* __restrict__ X, unsigned short* __restrict__ Xb)
{
  int i = (blockIdx.x * 256 + threadIdx.x) * 8;
  float4 v0 = *(const float4*)&X[i];
  float4 v1 = *(const float4*)&X[i + 4];
  unsigned short o[8];
  o[0] = f2b(v0.x); o[1] = f2b(v0.y); o[2] = f2b(v0.z); o[3] = f2b(v0.w);
  o[4] = f2b(v1.x); o[5] = f2b(v1.y); o[6] = f2b(v1.z); o[7] = f2b(v1.w);
  *(int4*)&Xb[i] = *(const int4*)o;
}

// ---------------- transpose + convert: W [K][N] fp32 -> WT [N][K] bf16, 64x64 tiles ----------------
__global__ __launch_bounds__(256) void transpose_cvt_kernel(
    const float* __restrict__ src0, const float* __restrict__ src1,
    unsigned short* __restrict__ dst0, unsigned short* __restrict__ dst1,
    int K, int N)
{
  const float* src = blockIdx.z ? src1 : src0;
  unsigned short* dst = blockIdx.z ? dst1 : dst0;
  __shared__ unsigned short t[64][72];
  const int n0 = blockIdx.x * 64, k0 = blockIdx.y * 64;
  const int tid = threadIdx.x;
  const int kl = tid >> 4, nl = (tid & 15) * 4;
#pragma unroll
  for (int i = 0; i < 4; ++i) {
    int k = kl + i * 16;
    float4 v = *(const float4*)&src[(size_t)(k0 + k) * N + n0 + nl];
    t[nl + 0][k] = f2b(v.x); t[nl + 1][k] = f2b(v.y);
    t[nl + 2][k] = f2b(v.z); t[nl + 3][k] = f2b(v.w);
  }
  __syncthreads();
  const int nl2 = tid >> 3, kc = (tid & 7) * 8;
#pragma unroll
  for (int i = 0; i < 2; ++i) {
    int n = nl2 + i * 32;
    *(int4*)&dst[(size_t)(n0 + n) * K + k0 + kc] = *(const int4*)&t[n][kc];
  }
}

// ---------------- dense fused gate+up (shared expert) ----------------
__global__ __launch_bounds__(256, 2) void gateup_kernel(
    const unsigned short* __restrict__ Xb,
    const unsigned short* __restrict__ Wgu,
    unsigned short* __restrict__ H)
{
  __shared__ __align__(16) unsigned short As[128 * 32];
  __shared__ __align__(16) unsigned short Bgs[64 * 32];
  __shared__ __align__(16) unsigned short Bus[64 * 32];
  const int m0 = blockIdx.y * 128;
  const int n0 = blockIdx.x * 64;
  const int tid = threadIdx.x;
  const int lane = tid & 63;
  const int w = tid >> 6;
  const int wm = (w & 1) * 64;
  const int wn = (w >> 1) * 32;
  const int c = lane & 15;
  const int q = lane >> 4;

  const unsigned short* Wg = Wgu;
  const unsigned short* Wu = Wgu + (size_t)HID * DIM;

  const int srow = tid >> 2;
  const int skofs = (tid & 3) * 8;
  const unsigned short* aptr0 = Xb + (size_t)(m0 + srow) * DIM + skofs;
  const unsigned short* aptr1 = Xb + (size_t)(m0 + srow + 64) * DIM + skofs;
  const unsigned short* gptr = Wg + (size_t)(n0 + srow) * DIM + skofs;
  const unsigned short* uptr = Wu + (size_t)(n0 + srow) * DIM + skofs;

  f32x4 accg[4][2], accu[4][2];
#pragma unroll
  for (int mi = 0; mi < 4; ++mi)
#pragma unroll
    for (int ni = 0; ni < 2; ++ni) {
      accg[mi][ni] = {0.f, 0.f, 0.f, 0.f};
      accu[mi][ni] = {0.f, 0.f, 0.f, 0.f};
    }

  for (int k0 = 0; k0 < DIM; k0 += 32) {
    __syncthreads();
    gload16(aptr0 + k0, &As[tid * 8]);
    gload16(aptr1 + k0, &As[2048 + tid * 8]);
    gload16(gptr + k0, &Bgs[tid * 8]);
    gload16(uptr + k0, &Bus[tid * 8]);
    __syncthreads();
    bf16x8 a[4], bg[2], bu[2];
#pragma unroll
    for (int mi = 0; mi < 4; ++mi)
      a[mi] = *(const bf16x8*)&As[(wm + mi * 16 + c) * 32 + q * 8];
#pragma unroll
    for (int ni = 0; ni < 2; ++ni) {
      bg[ni] = *(const bf16x8*)&Bgs[(wn + ni * 16 + c) * 32 + q * 8];
      bu[ni] = *(const bf16x8*)&Bus[(wn + ni * 16 + c) * 32 + q * 8];
    }
#pragma unroll
    for (int mi = 0; mi < 4; ++mi)
#pragma unroll
      for (int ni = 0; ni < 2; ++ni) {
        accg[mi][ni] = __builtin_amdgcn_mfma_f32_16x16x32_bf16(a[mi], bg[ni], accg[mi][ni], 0, 0, 0);
        accu[mi][ni] = __builtin_amdgcn_mfma_f32_16x16x32_bf16(a[mi], bu[ni], accu[mi][ni], 0, 0, 0);
      }
  }
#pragma unroll
  for (int mi = 0; mi < 4; ++mi)
#pragma unroll
    for (int ni = 0; ni < 2; ++ni)
#pragma unroll
      for (int r = 0; r < 4; ++r) {
        int row = wm + mi * 16 + q * 4 + r;
        int col = wn + ni * 16 + c;
        float g = accg[mi][ni][r];
        float u = accu[mi][ni][r];
        float h = (g / (1.f + __expf(-g))) * u;
        H[(size_t)(m0 + row) * HID + n0 + col] = f2b(h);
      }
}

// ---------------- sparse fused gate+up: gathered tokens, weight folded into H ----------------
__global__ __launch_bounds__(256, 2) void gateup_sparse_kernel(
    const unsigned short* __restrict__ Xb,
    const unsigned short* __restrict__ Wgu,
    const int* __restrict__ tok, const float* __restrict__ wgt,
    const int* __restrict__ cntofs, int e,
    unsigned short* __restrict__ H)
{
  const int cnt = cntofs[e];
  const int mb = blockIdx.y;
  if (mb * 128 >= cnt) return;
  const int ofs = cntofs[8 + e];

  __shared__ __align__(16) unsigned short As[128 * 32];
  __shared__ __align__(16) unsigned short Bgs[64 * 32];
  __shared__ __align__(16) unsigned short Bus[64 * 32];
  __shared__ float wl[128];

  const int n0 = blockIdx.x * 64;
  const int tid = threadIdx.x;
  const int lane = tid & 63;
  const int w = tid >> 6;
  const int wm = (w & 1) * 64;
  const int wn = (w >> 1) * 32;
  const int c = lane & 15;
  const int q = lane >> 4;

  if (tid < 128)
    wl[tid] = (mb * 128 + tid < cnt) ? wgt[ofs + mb * 128 + tid] : 0.f;

  const unsigned short* Wg = Wgu;
  const unsigned short* Wu = Wgu + (size_t)HID * DIM;

  const int srow = tid >> 2;
  const int skofs = (tid & 3) * 8;
  int s0 = mb * 128 + srow, s1 = s0 + 64;
  int t0 = (s0 < cnt) ? tok[ofs + s0] : 0;
  int t1 = (s1 < cnt) ? tok[ofs + s1] : 0;
  const unsigned short* aptr0 = Xb + (size_t)t0 * DIM + skofs;
  const unsigned short* aptr1 = Xb + (size_t)t1 * DIM + skofs;
  const unsigned short* gptr = Wg + (size_t)(n0 + srow) * DIM + skofs;
  const unsigned short* uptr = Wu + (size_t)(n0 + srow) * DIM + skofs;

  f32x4 accg[4][2], accu[4][2];
#pragma unroll
  for (int mi = 0; mi < 4; ++mi)
#pragma unroll
    for (int ni = 0; ni < 2; ++ni) {
      accg[mi][ni] = {0.f, 0.f, 0.f, 0.f};
      accu[mi][ni] = {0.f, 0.f, 0.f, 0.f};
    }

  for (int k0 = 0; k0 < DIM; k0 += 32) {
    __syncthreads();
    gload16(aptr0 + k0, &As[tid * 8]);
    gload16(aptr1 + k0, &As[2048 + tid * 8]);
    gload16(gptr + k0, &Bgs[tid * 8]);
    gload16(uptr + k0, &Bus[tid * 8]);
    __syncthreads();
    bf16x8 a[4], bg[2], bu[2];
#pragma unroll
    for (int mi = 0; mi < 4; ++mi)
      a[mi] = *(const bf16x8*)&As[(wm + mi * 16 + c) * 32 + q * 8];
#pragma unroll
    for (int ni = 0; ni < 2; ++ni) {
      bg[ni] = *(const bf16x8*)&Bgs[(wn + ni * 16 + c) * 32 + q * 8];
      bu[ni] = *(const bf16x8*)&Bus[(wn + ni * 16 + c) * 32 + q * 8];
    }
#pragma unroll
    for (int mi = 0; mi < 4; ++mi)
#pragma unroll
      for (int ni = 0; ni < 2; ++ni) {
        accg[mi][ni] = __builtin_amdgcn_mfma_f32_16x16x32_bf16(a[mi], bg[ni], accg[mi][ni], 0, 0, 0);
        accu[mi][ni] = __builtin_amdgcn_mfma_f32_16x16x32_bf16(a[mi], bu[ni], accu[mi][ni], 0, 0, 0);
      }
  }
#pragma unroll
  for (int mi = 0; mi < 4; ++mi)
#pragma unroll
    for (int ni = 0; ni < 2; ++ni)
#pragma unroll
      for (int r = 0; r < 4; ++r) {
        int row = wm + mi * 16 + q * 4 + r;
        int col = wn + ni * 16 + c;
        float g = accg[mi][ni][r];
        float u = accu[mi][ni][r];
        float h = (g / (1.f + __expf(-g))) * u * wl[row];
        H[(size_t)(mb * 128 + row) * HID + n0 + col] = f2b(h);
      }
}

// ---------------- dense down (shared expert, initializes out) ----------------
__global__ __launch_bounds__(256, 2) void down_dense_kernel(
    const unsigned short* __restrict__ Hm,
    const unsigned short* __restrict__ WdT,
    float* __restrict__ out)
{
  __shared__ __align__(16) unsigned short As[128 * 32];
  __shared__ __align__(16) unsigned short Bs[128 * 32];
  const int m0 = blockIdx.y * 128;
  const int n0 = blockIdx.x * 128;
  const int tid = threadIdx.x;
  const int lane = tid & 63;
  const int w4 = tid >> 6;
  const int wm = (w4 & 1) * 64;
  const int wn = (w4 >> 1) * 64;
  const int c = lane & 15;
  const int q = lane >> 4;

  const int srow = tid >> 2;
  const int skofs = (tid & 3) * 8;
  const unsigned short* aptr0 = Hm + (size_t)(m0 + srow) * HID + skofs;
  const unsigned short* aptr1 = Hm + (size_t)(m0 + srow + 64) * HID + skofs;
  const unsigned short* bptr0 = WdT + (size_t)(n0 + srow) * HID + skofs;
  const unsigned short* bptr1 = WdT + (size_t)(n0 + srow + 64) * HID + skofs;

  f32x4 acc[4][4];
#pragma unroll
  for (int mi = 0; mi < 4; ++mi)
#pragma unroll
    for (int ni = 0; ni < 4; ++ni) acc[mi][ni] = {0.f, 0.f, 0.f, 0.f};

  for (int k0 = 0; k0 < HID; k0 += 32) {
    __syncthreads();
    gload16(aptr0 + k0, &As[tid * 8]);
    gload16(aptr1 + k0, &As[2048 + tid * 8]);
    gload16(bptr0 + k0, &Bs[tid * 8]);
    gload16(bptr1 + k0, &Bs[2048 + tid * 8]);
    __syncthreads();
    bf16x8 a[4], b[4];
#pragma unroll
    for (int mi = 0; mi < 4; ++mi)
      a[mi] = *(const bf16x8*)&As[(wm + mi * 16 + c) * 32 + q * 8];
#pragma unroll
    for (int ni = 0; ni < 4; ++ni)
      b[ni] = *(const bf16x8*)&Bs[(wn + ni * 16 + c) * 32 + q * 8];
#pragma unroll
    for (int mi = 0; mi < 4; ++mi)
#pragma unroll
      for (int ni = 0; ni < 4; ++ni)
        acc[mi][ni] = __builtin_amdgcn_mfma_f32_16x16x32_bf16(a[mi], b[ni], acc[mi][ni], 0, 0, 0);
  }
#pragma unroll
  for (int mi = 0; mi < 4; ++mi)
#pragma unroll
    for (int r = 0; r < 4; ++r) {
      int trow = m0 + wm + mi * 16 + q * 4 + r;
#pragma unroll
      for (int ni = 0; ni < 4; ++ni) {
        int col = n0 + wn + ni * 16 + c;
        out[(size_t)trow * DIM + col] = acc[mi][ni][r];
      }
    }
}

// ---------------- sparse down: compacted H, scatter-accumulate ----------------
__global__ __launch_bounds__(256, 2) void down_sparse_kernel(
    const unsigned short* __restrict__ Hm,
    const unsigned short* __restrict__ WdT,
    const int* __restrict__ tok, const int* __restrict__ cntofs, int e,
    float* __restrict__ out)
{
  const int cnt = cntofs[e];
  const int mb = blockIdx.y;
  if (mb * 128 >= cnt) return;
  const int ofs = cntofs[8 + e];

  __shared__ __align__(16) unsigned short As[128 * 32];
  __shared__ __align__(16) unsigned short Bs[128 * 32];
  __shared__ int tl[128];
  const int n0 = blockIdx.x * 128;
  const int tid = threadIdx.x;
  const int lane = tid & 63;
  const int w4 = tid >> 6;
  const int wm = (w4 & 1) * 64;
  const int wn = (w4 >> 1) * 64;
  const int c = lane & 15;
  const int q = lane >> 4;

  if (tid < 128)
    tl[tid] = (mb * 128 + tid < cnt) ? tok[ofs + mb * 128 + tid] : 0;

  const int srow = tid >> 2;
  const int skofs = (tid & 3) * 8;
  const unsigned short* aptr0 = Hm + (size_t)(mb * 128 + srow) * HID + skofs;
  const unsigned short* aptr1 = Hm + (size_t)(mb * 128 + srow + 64) * HID + skofs;
  const unsigned short* bptr0 = WdT + (size_t)(n0 + srow) * HID + skofs;
  const unsigned short* bptr1 = WdT + (size_t)(n0 + srow + 64) * HID + skofs;

  f32x4 acc[4][4];
#pragma unroll
  for (int mi = 0; mi < 4; ++mi)
#pragma unroll
    for (int ni = 0; ni < 4; ++ni) acc[mi][ni] = {0.f, 0.f, 0.f, 0.f};

  for (int k0 = 0; k0 < HID; k0 += 32) {
    __syncthreads();
    gload16(aptr0 + k0, &As[tid * 8]);
    gload16(aptr1 + k0, &As[2048 + tid * 8]);
    gload16(bptr0 + k0, &Bs[tid * 8]);
    gload16(bptr1 + k0, &Bs[2048 + tid * 8]);
    __syncthreads();
    bf16x8 a[4], b[4];
#pragma unroll
    for (int mi = 0; mi < 4; ++mi)
      a[mi] = *(const bf16x8*)&As[(wm + mi * 16 + c) * 32 + q * 8];
#pragma unroll
    for (int ni = 0; ni < 4; ++ni)
      b[ni] = *(const bf16x8*)&Bs[(wn + ni * 16 + c) * 32 + q * 8];
#pragma unroll
    for (int mi = 0; mi < 4; ++mi)
#pragma unroll
      for (int ni = 0; ni < 4; ++ni)
        acc[mi][ni] = __builtin_amdgcn_mfma_f32_16x16x32_bf16(a[mi], b[ni], acc[mi][ni], 0, 0, 0);
  }
#pragma unroll
  for (int mi = 0; mi < 4; ++mi)
#pragma unroll
    for (int r = 0; r < 4; ++r) {
      int lr = wm + mi * 16 + q * 4 + r;
      if (mb * 128 + lr < cnt) {
        int t = tl[lr];
#pragma unroll
        for (int ni = 0; ni < 4; ++ni) {
          int col = n0 + wn + ni * 16 + c;
          out[(size_t)t * DIM + col] += acc[mi][ni][r];
        }
      }
    }
}

extern "C" void kernel_launch(void* const* d_in, const int* in_sizes, int n_in,
                              void* d_out, int out_size, void* d_ws, size_t ws_size,
                              hipStream_t stream) {
  (void)in_sizes; (void)n_in; (void)out_size; (void)ws_size;
  const float* x   = (const float*)d_in[0];
  const float* sg  = (const float*)d_in[1];
  const float* su  = (const float*)d_in[2];
  const float* sd  = (const float*)d_in[3];
  const float* rg  = (const float*)d_in[4];
  const float* ru  = (const float*)d_in[5];
  const float* rd  = (const float*)d_in[6];
  const float* wrr = (const float*)d_in[7];
  const float* rb  = (const float*)d_in[8];
  float* out = (float*)d_out;

  char* ws = (char*)d_ws;
  unsigned short* Xb  = (unsigned short*)ws;               // 16,777,216
  unsigned short* H   = (unsigned short*)(ws + 16777216);  // 46,137,344
  unsigned short* Wgu = (unsigned short*)(ws + 62914560);  // 11,534,336
  unsigned short* Wd  = (unsigned short*)(ws + 74448896);  //  5,767,168
  int*   tok          = (int*)(ws + 80216064);             //     65,536
  float* wgt          = (float*)(ws + 80281600);           //     65,536
  int*   cntofs       = (int*)(ws + 80347136);             //         64
  // eidx/ew parked inside H (consumed by build before any gateup writes H)
  int*   eidx = (int*)H;
  float* ew   = (float*)((char*)H + 32768);

  dim3 blk(256);
  router_kernel<<<dim3(TOKENS / 256), blk, 0, stream>>>(x, wrr, rb, eidx, ew);
  xcvt_kernel<<<dim3(TOKENS * DIM / (8 * 256)), blk, 0, stream>>>(x, Xb);
  build_kernel<<<dim3(1), blk, 0, stream>>>(eidx, ew, tok, wgt, cntofs);

  dim3 ggu(HID / 64, TOKENS / 128);
  dim3 gdn(DIM / 128, TOKENS / 128);
  dim3 tgu(HID / 64, DIM / 64, 2);
  dim3 tdn(DIM / 64, HID / 64, 1);

  for (int e = 0; e < 8; ++e) {
    const float* eg = (e == 0) ? sg : rg + (size_t)(e - 1) * DIM * HID;
    const float* eu = (e == 0) ? su : ru + (size_t)(e - 1) * DIM * HID;
    const float* ed = (e == 0) ? sd : rd + (size_t)(e - 1) * HID * DIM;
    transpose_cvt_kernel<<<tgu, blk, 0, stream>>>(eg, eu, Wgu, Wgu + (size_t)HID * DIM, DIM, HID);
    transpose_cvt_kernel<<<tdn, blk, 0, stream>>>(ed, ed, Wd, Wd, HID, DIM);
    if (e == 0) {
      gateup_kernel<<<ggu, blk, 0, stream>>>(Xb, Wgu, H);
      down_dense_kernel<<<gdn, blk, 0, stream>>>(H, Wd, out);
    } else {
      gateup_sparse_kernel<<<ggu, blk, 0, stream>>>(Xb, Wgu, tok, wgt, cntofs, e - 1, H);
      down_sparse_kernel<<<gdn, blk, 0, stream>>>(H, Wd, tok, cntofs, e - 1, out);
    }
  }
}